// Round 11
// baseline (150.995 us; speedup 1.0000x reference)
//
#include <hip/hip_runtime.h>

#define NE 8
#define TPB 8            // tokens per block
#define MAGIC 0x5A5A1234

typedef float f4 __attribute__((ext_vector_type(4)));

// One fused kernel. grid = T/TPB = 512 blocks x 512 threads (8 waves).
// Phase 1: wave w gates token t0+w (x: 3 coalesced f4 loads/lane; gate_w L1).
//          TokGate -> LDS; deterministic loss partials (fixed LDS slots,
//          no float atomics) -> ws; release flag.
// Phase 2: combine 8 tokens x 96 KB contiguous, nt stores, cand from L2.
// Phase 3: block 0 only, AFTER its combine: acquire-spin flags (already set
//          -> no wait), reduce 512x8 partials, write losses + gate_load.
__global__ void __launch_bounds__(512, 4)
fused_kernel(const f4* __restrict__ x,
             const f4* __restrict__ gate_w,
             const f4* __restrict__ cand,
             f4* __restrict__ out,
             float* __restrict__ part_psum,   // [nblk*8] ws
             float* __restrict__ part_cnt,    // [nblk*8] ws (counts as float)
             int* __restrict__ flags,         // [nblk] ws
             float* __restrict__ out_bal,
             float* __restrict__ out_imp,
             float* __restrict__ out_load,
             float* __restrict__ gate_out,
             int nblk, int D4, int V, int T) {
    __shared__ float s_w0[TPB], s_w1[TPB];
    __shared__ int   s_g0[TPB], s_g1[TPB];
    __shared__ float wps[TPB][NE];     // per-wave p[e] (fixed slots)
    __shared__ float sps[8][NE], scv[8][NE];

    int tid  = threadIdx.x;
    int wave = tid >> 6;               // 0..7
    int lane = tid & 63;
    int t0   = blockIdx.x * TPB;
    int t    = t0 + wave;

    // ---------------- phase 1: gating (one wave per token) ----------------
    {
        float acc[NE];
#pragma unroll
        for (int e = 0; e < NE; ++e) acc[e] = 0.f;
        const f4* xt = x + (size_t)t * D4;
#pragma unroll
        for (int it = 0; it < 3; ++it) {           // D4=192 = 3*64
            int d = lane + it * 64;
            f4 xv = xt[d];
#pragma unroll
            for (int e = 0; e < NE; ++e) {
                f4 gw = gate_w[e * D4 + d];        // L1/L2-hot (24 KB)
                acc[e] = fmaf(xv.x, gw.x,
                         fmaf(xv.y, gw.y,
                         fmaf(xv.z, gw.z,
                         fmaf(xv.w, gw.w, acc[e]))));
            }
        }
#pragma unroll
        for (int e = 0; e < NE; ++e) {
#pragma unroll
            for (int off = 32; off > 0; off >>= 1)
                acc[e] += __shfl_xor(acc[e], off);
        }
        float mx = acc[0];
#pragma unroll
        for (int e = 1; e < NE; ++e) mx = fmaxf(mx, acc[e]);
        float p[NE]; float s = 0.f;
#pragma unroll
        for (int e = 0; e < NE; ++e) { p[e] = expf(acc[e] - mx); s += p[e]; }
        float inv = 1.f / s;
#pragma unroll
        for (int e = 0; e < NE; ++e) p[e] *= inv;

        // top-2, first-index tie-break (strict >), static indexing
        float v0 = -1.f; int g0 = 0;
#pragma unroll
        for (int e = 0; e < NE; ++e)
            if (p[e] > v0) { v0 = p[e]; g0 = e; }
        float v1 = -1.f; int g1 = 0;
#pragma unroll
        for (int e = 0; e < NE; ++e)
            if (e != g0 && p[e] > v1) { v1 = p[e]; g1 = e; }

        if (lane == 0) {
            float wsum = v0 + v1;
            s_w0[wave] = v0 / wsum; s_w1[wave] = v1 / wsum;
            s_g0[wave] = g0;        s_g1[wave] = g1;
            gate_out[t * 2 + 0] = (float)g0;
            gate_out[t * 2 + 1] = (float)g1;
        }
        // deterministic partials: lane e owns wps[wave][e]
        float myp = 0.f;
#pragma unroll
        for (int e = 0; e < NE; ++e)
            if (lane == e) myp = p[e];
        if (lane < NE) wps[wave][lane] = myp;
    }
    __syncthreads();

    // per-block partials in fixed order (deterministic fp sums)
    if (tid < NE) {
        float ps = 0.f; float cv = 0.f;
#pragma unroll
        for (int w = 0; w < TPB; ++w) {
            ps += wps[w][tid];
            cv += (s_g0[w] == tid) ? 1.f : 0.f;
            cv += (s_g1[w] == tid) ? 1.f : 0.f;
        }
        part_psum[blockIdx.x * NE + tid] = ps;
        part_cnt[blockIdx.x * NE + tid]  = cv;
    }
    __threadfence();
    if (tid == 0)
        __hip_atomic_store(&flags[blockIdx.x], MAGIC,
                           __ATOMIC_RELEASE, __HIP_MEMORY_SCOPE_AGENT);

    // ---------------- phase 2: combine (nt stores, L2 cand reads) ----------
    for (int g = 0; g < TPB; ++g) {
        float w0 = s_w0[g], w1 = s_w1[g];
        const f4* c0 = cand + (size_t)s_g0[g] * V;
        const f4* c1 = cand + (size_t)s_g1[g] * V;
        f4* o = out + (size_t)(t0 + g) * V;
#pragma unroll 4
        for (int i = tid; i < V; i += 512) {
            f4 a = c0[i];
            f4 b = c1[i];
            __builtin_nontemporal_store(w0 * a + w1 * b, &o[i]);
        }
    }

    // ---------------- phase 3: block 0 tail — losses -----------------------
    if (blockIdx.x == 0) {
        for (int b = tid; b < nblk; b += 512)
            while (__hip_atomic_load(&flags[b], __ATOMIC_ACQUIRE,
                                     __HIP_MEMORY_SCOPE_AGENT) != MAGIC) {}
        __syncthreads();
        int e = tid & 7;
        float ps = 0.f, cv = 0.f;
        for (int b = tid >> 3; b < nblk; b += 64) {   // coalesced
            ps += part_psum[b * NE + e];
            cv += part_cnt[b * NE + e];
        }
        ps += __shfl_xor(ps, 8);  cv += __shfl_xor(cv, 8);
        ps += __shfl_xor(ps, 16); cv += __shfl_xor(cv, 16);
        ps += __shfl_xor(ps, 32); cv += __shfl_xor(cv, 32);
        if (lane < NE) { sps[wave][lane] = ps; scv[wave][lane] = cv; }
        __syncthreads();
        if (tid < NE) {
            ps = 0.f; cv = 0.f;
#pragma unroll
            for (int w = 0; w < 8; ++w) { ps += sps[w][tid]; cv += scv[w][tid]; }
            float sum_ps = ps, sum_c = cv;
            sum_ps += __shfl_xor(sum_ps, 4); sum_c += __shfl_xor(sum_c, 4);
            sum_ps += __shfl_xor(sum_ps, 2); sum_c += __shfl_xor(sum_c, 2);
            sum_ps += __shfl_xor(sum_ps, 1); sum_c += __shfl_xor(sum_c, 1);
            float mean = sum_ps * (1.f / NE);
            float bal_term = (ps / (float)T) * (cv / sum_c);
            float d = ps - mean;
            float dev = d * d;
            bal_term += __shfl_xor(bal_term, 4); dev += __shfl_xor(dev, 4);
            bal_term += __shfl_xor(bal_term, 2); dev += __shfl_xor(dev, 2);
            bal_term += __shfl_xor(bal_term, 1); dev += __shfl_xor(dev, 1);
            if (tid == 0) {
                *out_bal = (float)NE * bal_term;
                float var = dev * (1.f / (NE - 1));   // ddof=1
                *out_imp = var / (mean * mean);
            }
            out_load[tid] = cv;                        // gate_load as float
        }
    }
}

extern "C" void kernel_launch(void* const* d_in, const int* in_sizes, int n_in,
                              void* d_out, int out_size, void* d_ws, size_t ws_size,
                              hipStream_t stream) {
    const float* x      = (const float*)d_in[0];   // [B,S,D]
    const float* gate_w = (const float*)d_in[1];   // [E,D]
    const float* cand   = (const float*)d_in[2];   // [E,Nq,D]

    const int E  = NE;
    const int D  = in_sizes[1] / E;          // 768
    const int T  = in_sizes[0] / D;          // 4096
    const int Nq = in_sizes[2] / (E * D);    // 32

    float* outf = (float*)d_out;
    size_t OUT_N = (size_t)T * Nq * D;
    float* out_bal  = outf + OUT_N;
    float* out_imp  = out_bal + 1;
    float* out_load = out_imp + 1;
    float* gate_out = out_load + E;

    int nblk = T / TPB;                                    // 512
    float* part_psum = (float*)d_ws;                       // 16 KB
    float* part_cnt  = (float*)((char*)d_ws + 16384);      // 16 KB
    int*   flags     = (int*)((char*)d_ws + 32768);        // 2 KB

    int D4 = D / 4;                          // 192
    int V  = Nq * D / 4;                     // 6144

    fused_kernel<<<nblk, 512, 0, stream>>>((const f4*)x, (const f4*)gate_w,
                                           (const f4*)cand, (f4*)d_out,
                                           part_psum, part_cnt, flags,
                                           out_bal, out_imp, out_load,
                                           gate_out, nblk, D4, V, T);
}

// Round 12
// 85.762 us; speedup vs baseline: 1.7606x; 1.7606x over previous
//
#include <hip/hip_runtime.h>

#define NE 8       // experts
#define TOPK 2
#define CHUNK 256  // f4 elements of the [Nq,D] vector per block
#define TPG 64     // tokens per block (R4/R10 optimum)

typedef float f4 __attribute__((ext_vector_type(4)));

struct TokGate { float w0, w1; int g0, g1; };

// Streaming store: sc1 = no-allocate in L2 (keeps cand L2-resident) but
// DOES allocate in the 256MB MALL -> write-combining there, unlike nt
// which (hypothesis) skips the MALL and caps at ~5.5 TB/s line-granular HBM.
__device__ __forceinline__ void store_stream(f4* p, f4 v) {
    asm volatile("global_store_dwordx4 %0, %1, off sc1"
                 :: "v"(p), "v"(v) : "memory");
}

// ---------------- Kernel 1: gating (identical to R4/R10) ----------------
__global__ void gate_kernel(const f4* __restrict__ x,
                            const f4* __restrict__ gate_w,
                            float* __restrict__ part_psum,  // [nPart*8] ws
                            int* __restrict__ part_cnt,     // [nPart*8] ws
                            TokGate* __restrict__ tok,      // [T] ws
                            float* __restrict__ gate_out,   // [T*2] d_out
                            int T, int D4 /* D/4 */) {
    __shared__ float s_psum[NE];
    __shared__ int   s_cnt[NE];
    int tid = threadIdx.x;
    if (tid < NE) { s_psum[tid] = 0.f; s_cnt[tid] = 0; }
    __syncthreads();

    int wave = tid >> 6;
    int lane = tid & 63;
    int t = blockIdx.x * (blockDim.x >> 6) + wave;
    if (t < T) {
        float acc[NE];
#pragma unroll
        for (int e = 0; e < NE; ++e) acc[e] = 0.f;
        const f4* xt = x + (size_t)t * D4;
        for (int d = lane; d < D4; d += 64) {      // coalesced 16B/lane
            f4 xv = xt[d];
#pragma unroll
            for (int e = 0; e < NE; ++e) {
                f4 gw = gate_w[e * D4 + d];        // L1-hit (24 KB total)
                acc[e] = fmaf(xv.x, gw.x,
                         fmaf(xv.y, gw.y,
                         fmaf(xv.z, gw.z,
                         fmaf(xv.w, gw.w, acc[e]))));
            }
        }
#pragma unroll
        for (int e = 0; e < NE; ++e) {
#pragma unroll
            for (int off = 32; off > 0; off >>= 1)
                acc[e] += __shfl_xor(acc[e], off);
        }
        // softmax over 8 (all lanes redundantly)
        float mx = acc[0];
#pragma unroll
        for (int e = 1; e < NE; ++e) mx = fmaxf(mx, acc[e]);
        float p[NE]; float s = 0.f;
#pragma unroll
        for (int e = 0; e < NE; ++e) { p[e] = expf(acc[e] - mx); s += p[e]; }
        float inv = 1.f / s;
#pragma unroll
        for (int e = 0; e < NE; ++e) p[e] *= inv;

        // top-2 with first-index tie-break; static indexing only
        float v0 = -1.f; int g0 = 0;
#pragma unroll
        for (int e = 0; e < NE; ++e)
            if (p[e] > v0) { v0 = p[e]; g0 = e; }
        float v1 = -1.f; int g1 = 0;
#pragma unroll
        for (int e = 0; e < NE; ++e)
            if (e != g0 && p[e] > v1) { v1 = p[e]; g1 = e; }

        float wsum = v0 + v1;
        if (lane == 0) {
            TokGate tg;
            tg.w0 = v0 / wsum; tg.w1 = v1 / wsum;
            tg.g0 = g0; tg.g1 = g1;
            tok[t] = tg;
            gate_out[t * 2 + 0] = (float)g0;
            gate_out[t * 2 + 1] = (float)g1;
            atomicAdd(&s_cnt[g0], 1);      // LDS atomics only
            atomicAdd(&s_cnt[g1], 1);
        }
        float myp = 0.f;
#pragma unroll
        for (int e = 0; e < NE; ++e)
            if (lane == e) myp = p[e];
        if (lane < NE) atomicAdd(&s_psum[lane], myp);
    }
    __syncthreads();
    if (tid < NE) {
        part_psum[blockIdx.x * NE + tid] = s_psum[tid];
        part_cnt[blockIdx.x * NE + tid]  = s_cnt[tid];
    }
}

// ---------------- Kernel 2: combine + fused loss (R10, sc1 stores) --------
__global__ void __launch_bounds__(CHUNK)
combine_kernel(const f4* __restrict__ cand,
               const TokGate* __restrict__ tok,
               f4* __restrict__ out,
               int V /* Nq*D/4 */,
               const float* __restrict__ part_psum,
               const int* __restrict__ part_cnt,
               int nPart,
               float* __restrict__ out_bal,
               float* __restrict__ out_imp,
               float* __restrict__ out_load,
               int T) {
    __shared__ f4 s_cand[NE * CHUNK];
    __shared__ TokGate s_tok[TPG];
    __shared__ float sps[4][NE];
    __shared__ float scv[4][NE];
    int tid = threadIdx.x;

    if (blockIdx.x == 0 && blockIdx.y == 0) {
        // ---- loss reduction (1024 partials -> scalars) ----
        int lane = tid & 63;
        int wave = tid >> 6;
        int e = tid & 7;
        float ps = 0.f, cv = 0.f;
        for (int b = tid >> 3; b < nPart; b += 32) {   // coalesced 256B/wave
            ps += part_psum[b * NE + e];
            cv += (float)part_cnt[b * NE + e];
        }
        ps += __shfl_xor(ps, 8);  cv += __shfl_xor(cv, 8);
        ps += __shfl_xor(ps, 16); cv += __shfl_xor(cv, 16);
        ps += __shfl_xor(ps, 32); cv += __shfl_xor(cv, 32);
        if (lane < NE) { sps[wave][lane] = ps; scv[wave][lane] = cv; }
        __syncthreads();
        if (tid < NE) {
            ps = sps[0][tid] + sps[1][tid] + sps[2][tid] + sps[3][tid];
            cv = scv[0][tid] + scv[1][tid] + scv[2][tid] + scv[3][tid];
            float sum_ps = ps, sum_c = cv;
            sum_ps += __shfl_xor(sum_ps, 4); sum_c += __shfl_xor(sum_c, 4);
            sum_ps += __shfl_xor(sum_ps, 2); sum_c += __shfl_xor(sum_c, 2);
            sum_ps += __shfl_xor(sum_ps, 1); sum_c += __shfl_xor(sum_c, 1);
            float mean = sum_ps * (1.f / NE);
            float bal_term = (ps / (float)T) * (cv / sum_c);
            float d = ps - mean;
            float dev = d * d;
            bal_term += __shfl_xor(bal_term, 4); dev += __shfl_xor(dev, 4);
            bal_term += __shfl_xor(bal_term, 2); dev += __shfl_xor(dev, 2);
            bal_term += __shfl_xor(bal_term, 1); dev += __shfl_xor(dev, 1);
            if (tid == 0) {
                *out_bal = (float)NE * bal_term;
                float var = dev * (1.f / (NE - 1));   // ddof=1
                *out_imp = var / (mean * mean);
            }
            out_load[tid] = cv;                        // gate_load as float
        }
        __syncthreads();
    }

    // ---- combine (R10 structure, sc1 streaming stores) ----
    int base = blockIdx.x * CHUNK;
    int t0 = blockIdx.y * TPG;

#pragma unroll
    for (int e = 0; e < NE; ++e)
        s_cand[e * CHUNK + tid] = cand[(size_t)e * V + base + tid];
    if (tid < TPG) s_tok[tid] = tok[t0 + tid];
    __syncthreads();

#pragma unroll 4
    for (int k = 0; k < TPG; ++k) {
        TokGate tg = s_tok[k];
        f4 a = s_cand[tg.g0 * CHUNK + tid];
        f4 b = s_cand[tg.g1 * CHUNK + tid];
        f4 r = tg.w0 * a + tg.w1 * b;
        store_stream(&out[(size_t)(t0 + k) * V + base + tid], r);
    }
}

extern "C" void kernel_launch(void* const* d_in, const int* in_sizes, int n_in,
                              void* d_out, int out_size, void* d_ws, size_t ws_size,
                              hipStream_t stream) {
    const float* x      = (const float*)d_in[0];   // [B,S,D]
    const float* gate_w = (const float*)d_in[1];   // [E,D]
    const float* cand   = (const float*)d_in[2];   // [E,Nq,D]

    const int E  = NE;
    const int D  = in_sizes[1] / E;          // 768
    const int T  = in_sizes[0] / D;          // 4096
    const int Nq = in_sizes[2] / (E * D);    // 32

    float* outf = (float*)d_out;
    size_t OUT_N = (size_t)T * Nq * D;
    float* out_bal  = outf + OUT_N;
    float* out_imp  = out_bal + 1;
    float* out_load = out_imp + 1;
    float* gate_out = out_load + E;

    int nPart = (T + 3) / 4;                               // 1024 gate blocks
    float*   part_psum = (float*)d_ws;                     // 32 KB
    int*     part_cnt  = (int*)((char*)d_ws + 32768);      // 32 KB
    TokGate* tok       = (TokGate*)((char*)d_ws + 65536);  // 16*T B

    gate_kernel<<<nPart, 256, 0, stream>>>((const f4*)x, (const f4*)gate_w,
                                           part_psum, part_cnt, tok,
                                           gate_out, T, D / 4);

    int V = Nq * D / 4;                      // 6144 f4 per token
    dim3 grid(V / CHUNK, T / TPG);           // (24, 64) = 1536 blocks
    combine_kernel<<<grid, CHUNK, 0, stream>>>((const f4*)cand, tok,
                                               (f4*)d_out, V,
                                               part_psum, part_cnt, nPart,
                                               out_bal, out_imp, out_load, T);
}

// Round 13
// 82.256 us; speedup vs baseline: 1.8357x; 1.0426x over previous
//
#include <hip/hip_runtime.h>

#define NE 8       // experts
#define TOPK 2
#define CHUNK 256  // f4 elements of the [Nq,D] vector per block
#define TPG 64     // tokens per block (R4 optimum: 1536 blocks, 16 waves/CU)

typedef float f4 __attribute__((ext_vector_type(4)));

struct TokGate { float w0, w1; int g0, g1; };

// ---------------- Kernel 1: gating ----------------
__global__ void gate_kernel(const f4* __restrict__ x,
                            const f4* __restrict__ gate_w,
                            float* __restrict__ part_psum,  // [nPart*8] ws
                            int* __restrict__ part_cnt,     // [nPart*8] ws
                            TokGate* __restrict__ tok,      // [T] ws
                            float* __restrict__ gate_out,   // [T*2] d_out
                            int T, int D4 /* D/4 */) {
    __shared__ float s_psum[NE];
    __shared__ int   s_cnt[NE];
    int tid = threadIdx.x;
    if (tid < NE) { s_psum[tid] = 0.f; s_cnt[tid] = 0; }
    __syncthreads();

    int wave = tid >> 6;
    int lane = tid & 63;
    int t = blockIdx.x * (blockDim.x >> 6) + wave;
    if (t < T) {
        float acc[NE];
#pragma unroll
        for (int e = 0; e < NE; ++e) acc[e] = 0.f;
        const f4* xt = x + (size_t)t * D4;
        for (int d = lane; d < D4; d += 64) {      // coalesced 16B/lane
            f4 xv = xt[d];
#pragma unroll
            for (int e = 0; e < NE; ++e) {
                f4 gw = gate_w[e * D4 + d];        // L1-hit (24 KB total)
                acc[e] = fmaf(xv.x, gw.x,
                         fmaf(xv.y, gw.y,
                         fmaf(xv.z, gw.z,
                         fmaf(xv.w, gw.w, acc[e]))));
            }
        }
#pragma unroll
        for (int e = 0; e < NE; ++e) {
#pragma unroll
            for (int off = 32; off > 0; off >>= 1)
                acc[e] += __shfl_xor(acc[e], off);
        }
        // softmax over 8 (all lanes redundantly)
        float mx = acc[0];
#pragma unroll
        for (int e = 1; e < NE; ++e) mx = fmaxf(mx, acc[e]);
        float p[NE]; float s = 0.f;
#pragma unroll
        for (int e = 0; e < NE; ++e) { p[e] = expf(acc[e] - mx); s += p[e]; }
        float inv = 1.f / s;
#pragma unroll
        for (int e = 0; e < NE; ++e) p[e] *= inv;

        // top-2 with first-index tie-break; static indexing only
        float v0 = -1.f; int g0 = 0;
#pragma unroll
        for (int e = 0; e < NE; ++e)
            if (p[e] > v0) { v0 = p[e]; g0 = e; }
        float v1 = -1.f; int g1 = 0;
#pragma unroll
        for (int e = 0; e < NE; ++e)
            if (e != g0 && p[e] > v1) { v1 = p[e]; g1 = e; }

        float wsum = v0 + v1;
        if (lane == 0) {
            TokGate tg;
            tg.w0 = v0 / wsum; tg.w1 = v1 / wsum;
            tg.g0 = g0; tg.g1 = g1;
            tok[t] = tg;
            gate_out[t * 2 + 0] = (float)g0;
            gate_out[t * 2 + 1] = (float)g1;
            atomicAdd(&s_cnt[g0], 1);      // LDS atomics only
            atomicAdd(&s_cnt[g1], 1);
        }
        float myp = 0.f;
#pragma unroll
        for (int e = 0; e < NE; ++e)
            if (lane == e) myp = p[e];
        if (lane < NE) atomicAdd(&s_psum[lane], myp);
    }
    __syncthreads();
    if (tid < NE) {
        part_psum[blockIdx.x * NE + tid] = s_psum[tid];
        part_cnt[blockIdx.x * NE + tid]  = s_cnt[tid];
    }
}

// ---------------- Kernel 2: combine + fused loss ----------------
// Block (0,0) first runs the loss reduction (gate partials ready by stream
// order), then joins normal combine work. nt stores keep cand L2-resident.
__global__ void __launch_bounds__(CHUNK)
combine_kernel(const f4* __restrict__ cand,
               const TokGate* __restrict__ tok,
               f4* __restrict__ out,
               int V /* Nq*D/4 */,
               const float* __restrict__ part_psum,
               const int* __restrict__ part_cnt,
               int nPart,
               float* __restrict__ out_bal,
               float* __restrict__ out_imp,
               float* __restrict__ out_load,
               int T) {
    __shared__ f4 s_cand[NE * CHUNK];
    __shared__ TokGate s_tok[TPG];
    __shared__ float sps[4][NE];
    __shared__ float scv[4][NE];
    int tid = threadIdx.x;

    if (blockIdx.x == 0 && blockIdx.y == 0) {
        // ---- loss reduction (1024 partials -> scalars), ~1.5 us ----
        int lane = tid & 63;
        int wave = tid >> 6;
        int e = tid & 7;
        float ps = 0.f, cv = 0.f;
        for (int b = tid >> 3; b < nPart; b += 32) {   // coalesced 256B/wave
            ps += part_psum[b * NE + e];
            cv += (float)part_cnt[b * NE + e];
        }
        ps += __shfl_xor(ps, 8);  cv += __shfl_xor(cv, 8);
        ps += __shfl_xor(ps, 16); cv += __shfl_xor(cv, 16);
        ps += __shfl_xor(ps, 32); cv += __shfl_xor(cv, 32);
        if (lane < NE) { sps[wave][lane] = ps; scv[wave][lane] = cv; }
        __syncthreads();
        if (tid < NE) {
            ps = sps[0][tid] + sps[1][tid] + sps[2][tid] + sps[3][tid];
            cv = scv[0][tid] + scv[1][tid] + scv[2][tid] + scv[3][tid];
            float sum_ps = ps, sum_c = cv;
            sum_ps += __shfl_xor(sum_ps, 4); sum_c += __shfl_xor(sum_c, 4);
            sum_ps += __shfl_xor(sum_ps, 2); sum_c += __shfl_xor(sum_c, 2);
            sum_ps += __shfl_xor(sum_ps, 1); sum_c += __shfl_xor(sum_c, 1);
            float mean = sum_ps * (1.f / NE);
            float bal_term = (ps / (float)T) * (cv / sum_c);
            float d = ps - mean;
            float dev = d * d;
            bal_term += __shfl_xor(bal_term, 4); dev += __shfl_xor(dev, 4);
            bal_term += __shfl_xor(bal_term, 2); dev += __shfl_xor(dev, 2);
            bal_term += __shfl_xor(bal_term, 1); dev += __shfl_xor(dev, 1);
            if (tid == 0) {
                *out_bal = (float)NE * bal_term;
                float var = dev * (1.f / (NE - 1));   // ddof=1
                *out_imp = var / (mean * mean);
            }
            out_load[tid] = cv;                        // gate_load as float
        }
        __syncthreads();
    }

    // ---- combine ----
    int base = blockIdx.x * CHUNK;
    int t0 = blockIdx.y * TPG;

#pragma unroll
    for (int e = 0; e < NE; ++e)
        s_cand[e * CHUNK + tid] = cand[(size_t)e * V + base + tid];
    if (tid < TPG) s_tok[tid] = tok[t0 + tid];
    __syncthreads();

#pragma unroll 4
    for (int k = 0; k < TPG; ++k) {
        TokGate tg = s_tok[k];
        f4 a = s_cand[tg.g0 * CHUNK + tid];
        f4 b = s_cand[tg.g1 * CHUNK + tid];
        f4 r = tg.w0 * a + tg.w1 * b;
        __builtin_nontemporal_store(r, &out[(size_t)(t0 + k) * V + base + tid]);
    }
}

extern "C" void kernel_launch(void* const* d_in, const int* in_sizes, int n_in,
                              void* d_out, int out_size, void* d_ws, size_t ws_size,
                              hipStream_t stream) {
    const float* x      = (const float*)d_in[0];   // [B,S,D]
    const float* gate_w = (const float*)d_in[1];   // [E,D]
    const float* cand   = (const float*)d_in[2];   // [E,Nq,D]

    const int E  = NE;
    const int D  = in_sizes[1] / E;          // 768
    const int T  = in_sizes[0] / D;          // 4096
    const int Nq = in_sizes[2] / (E * D);    // 32

    float* outf = (float*)d_out;
    size_t OUT_N = (size_t)T * Nq * D;
    float* out_bal  = outf + OUT_N;
    float* out_imp  = out_bal + 1;
    float* out_load = out_imp + 1;
    float* gate_out = out_load + E;

    int nPart = (T + 3) / 4;                               // 1024 gate blocks
    float*   part_psum = (float*)d_ws;                     // 32 KB
    int*     part_cnt  = (int*)((char*)d_ws + 32768);      // 32 KB
    TokGate* tok       = (TokGate*)((char*)d_ws + 65536);  // 16*T B

    gate_kernel<<<nPart, 256, 0, stream>>>((const f4*)x, (const f4*)gate_w,
                                           part_psum, part_cnt, tok,
                                           gate_out, T, D / 4);

    int V = Nq * D / 4;                      // 6144 f4 per token
    dim3 grid(V / CHUNK, T / TPG);           // (24, 64) = 1536 blocks
    combine_kernel<<<grid, CHUNK, 0, stream>>>((const f4*)cand, tok,
                                               (f4*)d_out, V,
                                               part_psum, part_cnt, nPart,
                                               out_bal, out_imp, out_load, T);
}